// Round 4
// baseline (163.636 us; speedup 1.0000x reference)
//
#include <hip/hip_runtime.h>
#include <math.h>

// InfoNCE loss, K=3, SKIP=1, NEG=64
// z,c: (64,256,14,14) f32; Wk: (3,256,256) f32; neg_idx_k: (rows_k*64,) i32
// rows_k = 10752, 9856, 8960. row = (h*14+w)*64 + b.
//
// Pipeline (4 launches): prep, proj (unchanged, verified), loss (barrier-free
// per-wave pipeline: 3072 one-wave blocks, each streams ~10 rows; per row
// 4 m-tiles + tail gathered via wide DMA into a 3-deep LDS ring with counted
// s_waitcnt vmcnt(N) (never a full drain in steady state); online softmax per
// tile; idx/ctx prefetched a full row ahead), reduce.

typedef short bf16x8 __attribute__((ext_vector_type(8)));
typedef float f32x4 __attribute__((ext_vector_type(4)));

#define VWAIT(N) asm volatile("s_waitcnt vmcnt(" #N ")" ::: "memory")
#define SB() __builtin_amdgcn_sched_barrier(0)

static __device__ __forceinline__ unsigned short f2bf(float f) {
    union { float f; unsigned int u; } x; x.f = f;
    unsigned int r = x.u + 0x7fffu + ((x.u >> 16) & 1u);   // RNE
    return (unsigned short)(r >> 16);
}

// float -> OCP e4m3fn (RNE, saturate to 448, subnormals handled)
static __device__ __forceinline__ unsigned char f2e4m3(float f) {
    union { float f; unsigned int u; } x; x.f = f;
    unsigned int s = (x.u >> 24) & 0x80u;
    float af = fabsf(f);
    if (af > 448.f) af = 448.f;
    x.f = af;
    unsigned int u = x.u;
    int e = (int)(u >> 23) - 127;
    unsigned int out;
    if (af == 0.f) {
        out = 0u;
    } else if (e < -6) {
        int mq = (int)rintf(af * 512.f);          // multiples of 2^-9
        out = (mq >= 8) ? 0x08u : (unsigned int)mq;
    } else {
        unsigned int r = u + 0x7FFFFu + ((u >> 20) & 1u);  // RNE, drop 20 bits
        int e2 = (int)(r >> 23) - 127;
        if (e2 > 8) out = 0x7Eu;                  // 448
        else out = (unsigned int)(((e2 + 7) << 3) | ((r >> 20) & 7u));
    }
    return (unsigned char)(s | out);
}

// async global->LDS DMA: per-lane global addr, dest = uniform base + lane*sz
static __device__ __forceinline__ void gload_lds4(const void* g, void* l) {
    __builtin_amdgcn_global_load_lds(
        (const __attribute__((address_space(1))) void*)g,
        (__attribute__((address_space(3))) void*)l, 4, 0, 0);
}
static __device__ __forceinline__ void gload_lds16(const void* g, void* l) {
    __builtin_amdgcn_global_load_lds(
        (const __attribute__((address_space(1))) void*)g,
        (__attribute__((address_space(3))) void*)l, 16, 0, 0);
}

// prep: blocks [0,768): Wk->bf16 (block0 also zeroes out[0]);
// [768,1792): z -> zt bf16 transposed; [1792,2816): c -> ct8 fp8 transposed.
__global__ __launch_bounds__(256)
void prep_kernel(const float* __restrict__ z, const float* __restrict__ c,
                 const float* __restrict__ Wk,
                 unsigned short* __restrict__ zt, unsigned char* __restrict__ ct8,
                 unsigned short* __restrict__ wkb, float* __restrict__ out) {
    __shared__ float tile[16][201];
    const int tid = threadIdx.x;
    int x = blockIdx.x;
    if (x < 768) {
        int i = x * 256 + tid;
        wkb[i] = f2bf(Wk[i]);
        if (x == 0 && tid == 0) out[0] = 0.f;
        return;
    }
    const bool isz = x < 1792;
    const int local = isz ? (x - 768) : (x - 1792);
    const float* src = isz ? z : c;
    const int b  = local & 63;
    const int c0 = (local >> 6) << 4;
    for (int i = tid; i < 16 * 196; i += 256) {
        int cc = i / 196;
        int hw = i - cc * 196;
        tile[cc][hw] = src[(size_t)((b << 8) + c0 + cc) * 196 + hw];
    }
    __syncthreads();
    if (isz) {
        for (int i = tid; i < 196 * 16; i += 256) {
            int hw = i >> 4, cc = i & 15;
            zt[(size_t)((hw << 6) + b) * 256 + c0 + cc] = f2bf(tile[cc][hw]);
        }
    } else {
        for (int i = tid; i < 196 * 16; i += 256) {
            int hw = i >> 4, cc = i & 15;
            ct8[(size_t)((hw << 6) + b) * 256 + c0 + cc] = f2e4m3(tile[cc][hw]);
        }
    }
}

// proj: ztwk8[k][row][o] = fp8(sum_c zt[zrow][c] * wk[k][o][c])
#define PSTR 528
__global__ __launch_bounds__(256)
void proj_mfma_kernel(const unsigned short* __restrict__ zt,
                      const unsigned short* __restrict__ wkb,
                      unsigned char* __restrict__ ztwk) {
    __shared__ __align__(16) unsigned char smem[(64 + 32) * PSTR];  // 50688 B
    unsigned char* smA = smem;
    unsigned char* smB = smem + 64 * PSTR;

    int x = blockIdx.y;
    int k, hw;
    if (x < 168)      { k = 0; hw = x; }
    else if (x < 322) { k = 1; hw = x - 168; }
    else              { k = 2; hw = x - 322; }
    const int o0 = blockIdx.x << 5;                    // 32 outs per block
    const int row0  = hw << 6;
    const int zrow0 = row0 + (((k + 2) * 14) << 6);    // h' = h + (k_idx+2)
    unsigned char* zo = ztwk + (size_t)k * 10752 * 256;

    const int tid = threadIdx.x;
    const unsigned char* zsrc = (const unsigned char*)(zt + (size_t)zrow0 * 256);
    const unsigned char* bsrc = (const unsigned char*)(wkb + ((size_t)k << 16) + o0 * 256);

    #pragma unroll
    for (int i = 0; i < 8; ++i) {          // A: 32 KB contiguous
        int sb = ((i << 8) + tid) << 4;
        int r = sb >> 9, off = sb & 511;
        *(int4*)(smA + r * PSTR + off) = *(const int4*)(zsrc + sb);
    }
    #pragma unroll
    for (int i = 0; i < 4; ++i) {          // B: 16 KB contiguous
        int sb = ((i << 8) + tid) << 4;
        int r = sb >> 9, off = sb & 511;
        *(int4*)(smB + r * PSTR + off) = *(const int4*)(bsrc + sb);
    }
    __syncthreads();

    const int wv = tid >> 6, lane = tid & 63;
    const int m = lane & 15, kq = lane >> 4;
    f32x4 acc[2] = {};
    const unsigned short* aP  = (const unsigned short*)(smA + (size_t)((wv << 4) + m) * PSTR) + (kq << 3);
    const unsigned short* bP0 = (const unsigned short*)(smB + (size_t)m * PSTR) + (kq << 3);
    const unsigned short* bP1 = (const unsigned short*)(smB + (size_t)(16 + m) * PSTR) + (kq << 3);
    #pragma unroll
    for (int kk = 0; kk < 256; kk += 32) {
        bf16x8 af = *(const bf16x8*)(aP  + kk);
        bf16x8 b0 = *(const bf16x8*)(bP0 + kk);
        bf16x8 b1 = *(const bf16x8*)(bP1 + kk);
        acc[0] = __builtin_amdgcn_mfma_f32_16x16x32_bf16(af, b0, acc[0], 0, 0, 0);
        acc[1] = __builtin_amdgcn_mfma_f32_16x16x32_bf16(af, b1, acc[1], 0, 0, 0);
    }
    __syncthreads();
    unsigned char* cs = smA;               // [64 rows][40 B]
    #pragma unroll
    for (int nt = 0; nt < 2; ++nt)
        #pragma unroll
        for (int r = 0; r < 4; ++r)
            cs[(size_t)((wv << 4) + (kq << 2) + r) * 40 + (nt << 4) + m] =
                f2e4m3(acc[nt][r]);
    __syncthreads();
    {
        int r = tid >> 2, off = (tid & 3) << 3;
        unsigned long long v = *(const unsigned long long*)(cs + (size_t)r * 40 + off);
        *(unsigned long long*)(zo + (size_t)(row0 + r) * 256 + o0 + off) = v;
    }
}

// ---------------------------------------------------------------------------
// loss: barrier-free per-wave pipeline.
// Stream s (block) handles rows gr = s, s+3072, ... (~10 rows).
// Per row: 65 slots -> tiles 0..3 (16 slots each, 4 wide DMAs) + tail tile 4
// (slots 64..67, 1 wide DMA; junk D-rows masked -- each D-row depends only on
// its own A-row). Groups: G0=[ctx,idx(+2),T0 x4](6) G1..G3=[Tt x4](4) G4=[1].
// Issue schedule per phase t: WAIT W_t ; ds_read frags ; SB ; issue X_t ;
// MFMA + online softmax.  X = {G2,G3,G4,G0',G1'}; W = {4,4,4,1,6}
// (ledger: W_t = #instrs outstanding younger than group G_t). Last row:
// W_4 = 0, no X_3/4.  Swizzle (verified R2): source 16B-block b holds global
// block b^(slot&7); reader asoff = m*256 + ((kq<<3) ^ ((m&7)<<4)), af at
// asoff ^ (kk<<5).
// ---------------------------------------------------------------------------
#define NSTREAM 3072

static __device__ __forceinline__ void rowmeta(int gr, int* k, int* row) {
    if (gr < 10752)      { *k = 0; *row = gr; }
    else if (gr < 20608) { *k = 1; *row = gr - 10752; }
    else                 { *k = 2; *row = gr - 20608; }
}

// full 16-slot tile t (0..3): 4 wide DMAs, 4 slots each
static __device__ __forceinline__ void issue_tile(
    unsigned char* tbuf, int t, int myidx, int grow,
    const unsigned char* f8, int lane) {
    const int lg = lane >> 4;
    const int c16b = (lane & 15) << 4;
    #pragma unroll
    for (int q = 0; q < 4; ++q) {
        int s = (t << 4) + (q << 2) + lg;                 // slot 0..63 here
        int sel = s - 1; if (sel < 0) sel = 0;
        int srow = __shfl(myidx, sel);
        if (s == 0) srow = grow;                          // slot 0 = main row
        int soff = c16b ^ (((((q & 1) << 2) + lg) & 7) << 4);
        gload_lds16(f8 + (size_t)srow * 256 + soff, tbuf + (q << 10));
    }
}
// tail tile: slots 64..67 (1 DMA); only local slot 0 (slot 64) is consumed
static __device__ __forceinline__ void issue_tail(
    unsigned char* tbuf, int myidx, const unsigned char* f8, int lane) {
    const int lg = lane >> 4;
    const int c16b = (lane & 15) << 4;
    int srow = __shfl(myidx, 63);                         // idx[63] -> slot 64
    int soff = c16b ^ ((lg & 7) << 4);
    gload_lds16(f8 + (size_t)srow * 256 + soff, tbuf);
}

__global__ __launch_bounds__(64)
void loss_mfma_kernel(const unsigned char* __restrict__ ct8,
                      const unsigned char* __restrict__ ztwk8,
                      const int* __restrict__ n0, const int* __restrict__ n1,
                      const int* __restrict__ n2, float* __restrict__ rowloss) {
    __shared__ __align__(16) unsigned char tb[3][4096];
    __shared__ __align__(16) unsigned char cx[2][256];
    __shared__ int ib[2][64];

    const int lane = threadIdx.x;
    const int m = lane & 15, kq = lane >> 4;
    const int stream = blockIdx.x;
    const int n = (29568 - stream + NSTREAM - 1) / NSTREAM;   // 9 or 10

    const int asoff = m * 256 + ((kq << 3) ^ ((m & 7) << 4));

    int gr = stream;
    int k, row; rowmeta(gr, &k, &row);
    const unsigned char* f8 = ztwk8 + (size_t)k * 10752 * 256;
    float wkcur = (k == 0) ? (1.f / (3.f * 10752.f))
                : (k == 1) ? (1.f / (3.f * 9856.f))
                           : (1.f / (3.f * 8960.f));

    // ---- prologue: idx(0); wait; G0(0) = [ctx0, idx1, T(0,0)]; G1(0) = T(0,1)
    {
        const int* nb = (k == 0) ? n0 : (k == 1) ? n1 : n2;
        gload_lds4(nb + ((size_t)row << 6) + lane, ib[0]);
    }
    VWAIT(0); SB();
    int myidx = ib[0][lane];
    {
        gload_lds4(ct8 + (size_t)row * 256 + (lane << 2), cx[0]);
        int gr1 = gr + NSTREAM;
        int k1, row1; rowmeta(gr1, &k1, &row1);
        const int* nb1 = (k1 == 0) ? n0 : (k1 == 1) ? n1 : n2;
        gload_lds4(nb1 + ((size_t)row1 << 6) + lane, ib[1]);
        issue_tile(tb[0], 0, myidx, row, f8, lane);
        issue_tile(tb[1], 1, myidx, row, f8, lane);
    }

    float lacc = 0.f;
    int r0 = 0;
    int myidx_nx = 0;

    for (int i = 0; i < n; ++i) {
        const bool last = (i == n - 1);
        int r1 = r0 + 1; if (r1 == 3) r1 = 0;
        int r2 = r1 + 1; if (r2 == 3) r2 = 0;

        int gr1 = gr + NSTREAM;
        int k1 = k, row1 = row;
        const unsigned char* f81 = f8;
        if (!last) {
            rowmeta(gr1, &k1, &row1);
            f81 = ztwk8 + (size_t)k1 * 10752 * 256;
        }

        long long bf[8], af[8];
        f32x4 a;
        float m_run, s_run, mainv;

        // ---------- phase 0: tile 0 from r0; issue G2 -> r2
        VWAIT(4); SB();
        {
            const unsigned char* cpx = cx[i & 1] + (kq << 3);
            #pragma unroll
            for (int kk = 0; kk < 8; ++kk) bf[kk] = *(const long long*)(cpx + (kk << 5));
            #pragma unroll
            for (int kk = 0; kk < 8; ++kk) af[kk] = *(const long long*)(tb[r0] + (asoff ^ (kk << 5)));
        }
        SB();
        issue_tile(tb[r2], 2, myidx, row, f8, lane);
        a = f32x4{0.f, 0.f, 0.f, 0.f};
        #pragma unroll
        for (int kk = 0; kk < 8; ++kk)
            a = __builtin_amdgcn_mfma_f32_16x16x32_fp8_fp8(af[kk], bf[kk], a, 0, 0, 0);
        {
            float tm = fmaxf(fmaxf(a[0], a[1]), fmaxf(a[2], a[3]));
            tm = fmaxf(tm, __shfl_xor(tm, 16));
            tm = fmaxf(tm, __shfl_xor(tm, 32));
            m_run = tm;
            s_run = __expf(a[0] - tm) + __expf(a[1] - tm)
                  + __expf(a[2] - tm) + __expf(a[3] - tm);
            mainv = a[0];                      // slot 0 at kq==0 lanes
        }

        // ---------- phase 1: tile 1 from r1; issue G3 -> r0
        VWAIT(4); SB();
        #pragma unroll
        for (int kk = 0; kk < 8; ++kk) af[kk] = *(const long long*)(tb[r1] + (asoff ^ (kk << 5)));
        SB();
        issue_tile(tb[r0], 3, myidx, row, f8, lane);
        a = f32x4{0.f, 0.f, 0.f, 0.f};
        #pragma unroll
        for (int kk = 0; kk < 8; ++kk)
            a = __builtin_amdgcn_mfma_f32_16x16x32_fp8_fp8(af[kk], bf[kk], a, 0, 0, 0);
        {
            float tm = fmaxf(fmaxf(a[0], a[1]), fmaxf(a[2], a[3]));
            tm = fmaxf(tm, __shfl_xor(tm, 16));
            tm = fmaxf(tm, __shfl_xor(tm, 32));
            float mnew = fmaxf(m_run, tm);
            s_run = s_run * __expf(m_run - mnew)
                  + __expf(a[0] - mnew) + __expf(a[1] - mnew)
                  + __expf(a[2] - mnew) + __expf(a[3] - mnew);
            m_run = mnew;
        }

        // ---------- phase 2: tile 2 from r2; issue G4 (tail) -> r1
        VWAIT(4); SB();
        #pragma unroll
        for (int kk = 0; kk < 8; ++kk) af[kk] = *(const long long*)(tb[r2] + (asoff ^ (kk << 5)));
        SB();
        issue_tail(tb[r1], myidx, f8, lane);
        a = f32x4{0.f, 0.f, 0.f, 0.f};
        #pragma unroll
        for (int kk = 0; kk < 8; ++kk)
            a = __builtin_amdgcn_mfma_f32_16x16x32_fp8_fp8(af[kk], bf[kk], a, 0, 0, 0);
        {
            float tm = fmaxf(fmaxf(a[0], a[1]), fmaxf(a[2], a[3]));
            tm = fmaxf(tm, __shfl_xor(tm, 16));
            tm = fmaxf(tm, __shfl_xor(tm, 32));
            float mnew = fmaxf(m_run, tm);
            s_run = s_run * __expf(m_run - mnew)
                  + __expf(a[0] - mnew) + __expf(a[1] - mnew)
                  + __expf(a[2] - mnew) + __expf(a[3] - mnew);
            m_run = mnew;
        }

        // ---------- phase 3: tile 3 from r0; issue G0(i+1) -> ctx,idx,T0 -> r2
        VWAIT(1); SB();
        #pragma unroll
        for (int kk = 0; kk < 8; ++kk) af[kk] = *(const long long*)(tb[r0] + (asoff ^ (kk << 5)));
        if (!last) myidx_nx = ib[(i + 1) & 1][lane];
        SB();
        if (!last) {
            gload_lds4(ct8 + (size_t)row1 * 256 + (lane << 2), cx[(i + 1) & 1]);
            int gr2 = gr + 2 * NSTREAM;
            int k2 = k1, row2 = row1;
            if (gr2 < 29568) rowmeta(gr2, &k2, &row2);    // else dummy (safe addr)
            const int* nb2 = (k2 == 0) ? n0 : (k2 == 1) ? n1 : n2;
            gload_lds4(nb2 + ((size_t)row2 << 6) + lane, ib[i & 1]);
            issue_tile(tb[r2], 0, myidx_nx, row1, f81, lane);
        }
        a = f32x4{0.f, 0.f, 0.f, 0.f};
        #pragma unroll
        for (int kk = 0; kk < 8; ++kk)
            a = __builtin_amdgcn_mfma_f32_16x16x32_fp8_fp8(af[kk], bf[kk], a, 0, 0, 0);
        {
            float tm = fmaxf(fmaxf(a[0], a[1]), fmaxf(a[2], a[3]));
            tm = fmaxf(tm, __shfl_xor(tm, 16));
            tm = fmaxf(tm, __shfl_xor(tm, 32));
            float mnew = fmaxf(m_run, tm);
            s_run = s_run * __expf(m_run - mnew)
                  + __expf(a[0] - mnew) + __expf(a[1] - mnew)
                  + __expf(a[2] - mnew) + __expf(a[3] - mnew);
            m_run = mnew;
        }

        // ---------- phase 4: tail tile from r1 (slot 64 = kq0/reg0 only);
        //            issue G1(i+1) -> r0
        if (last) { VWAIT(0); SB(); } else { VWAIT(6); SB(); }
        #pragma unroll
        for (int kk = 0; kk < 8; ++kk) af[kk] = *(const long long*)(tb[r1] + (asoff ^ (kk << 5)));
        SB();
        if (!last) issue_tile(tb[r0], 1, myidx_nx, row1, f81, lane);
        a = f32x4{0.f, 0.f, 0.f, 0.f};
        #pragma unroll
        for (int kk = 0; kk < 8; ++kk)
            a = __builtin_amdgcn_mfma_f32_16x16x32_fp8_fp8(af[kk], bf[kk], a, 0, 0, 0);
        {
            float v = (kq == 0) ? a[0] : -1e30f;          // only slot 64 valid
            float tm = fmaxf(v, __shfl_xor(v, 16));
            tm = fmaxf(tm, __shfl_xor(tm, 32));
            float mnew = fmaxf(m_run, tm);
            s_run = s_run * __expf(m_run - mnew)
                  + ((kq == 0) ? __expf(a[0] - mnew) : 0.f);
            m_run = mnew;
        }

        // ---------- row finish (all lanes redundantly)
        s_run += __shfl_xor(s_run, 16);
        s_run += __shfl_xor(s_run, 32);
        float mainl = __shfl(mainv, 0);
        float p0 = __expf(mainl - m_run) / s_run;
        lacc += -logf(p0 + 1e-11f) * wkcur;

        // ---------- advance
        gr = gr1;
        if (!last) {
            k = k1; row = row1; f8 = f81; myidx = myidx_nx;
            wkcur = (k == 0) ? (1.f / (3.f * 10752.f))
                  : (k == 1) ? (1.f / (3.f * 9856.f))
                             : (1.f / (3.f * 8960.f));
        }
        r0 = r2;
    }

    if (lane == 0) rowloss[stream] = lacc;
}

// Sum rowloss[0..3072) -> out[0] (out zeroed in prep)
__global__ __launch_bounds__(256)
void reduce_kernel(const float* __restrict__ rl, float* __restrict__ out) {
    float s = rl[blockIdx.x * 256 + threadIdx.x];
    #pragma unroll
    for (int off = 32; off >= 1; off >>= 1) s += __shfl_xor(s, off);
    if ((threadIdx.x & 63) == 0) atomicAdd(out, s);
}

extern "C" void kernel_launch(void* const* d_in, const int* in_sizes, int n_in,
                              void* d_out, int out_size, void* d_ws, size_t ws_size,
                              hipStream_t stream) {
    const float* z  = (const float*)d_in[0];
    const float* c  = (const float*)d_in[1];
    const float* Wk = (const float*)d_in[2];
    const int* negs[3] = {(const int*)d_in[3], (const int*)d_in[4], (const int*)d_in[5]};
    float* out = (float*)d_out;

    char* p = (char*)d_ws;
    unsigned short* zt      = (unsigned short*)p;   p += (size_t)196 * 64 * 256 * 2;
    unsigned short* wkb     = (unsigned short*)p;   p += (size_t)3 * 65536 * 2;
    unsigned char*  ct8     = (unsigned char*)p;    p += (size_t)196 * 64 * 256;
    unsigned char*  ztwk8   = (unsigned char*)p;    p += (size_t)3 * 10752 * 256;
    float*          rowloss = (float*)p;

    prep_kernel<<<2816, 256, 0, stream>>>(z, c, Wk, zt, ct8, wkb, out);
    proj_mfma_kernel<<<dim3(8, 462), 256, 0, stream>>>(zt, wkb, ztwk8);
    loss_mfma_kernel<<<NSTREAM, 64, 0, stream>>>(ct8, ztwk8, negs[0], negs[1],
                                                 negs[2], rowloss);
    reduce_kernel<<<12, 256, 0, stream>>>(rowloss, out);
}